// Round 1
// baseline (310.163 us; speedup 1.0000x reference)
//
#include <hip/hip_runtime.h>
#include <cstdint>
#include <cstddef>

// PointerNetwork: B=256, S=512, H=128, CHAR/CLASS=10, OUT=64, WE=32
// Design:
//  - active-step skipping (char_ids==0 only, ~51/512 steps per row)
//  - XW1[w] = (emb_char[0]+emb_word[w]@Wwc+bwc)@l1_Wx + l1_b  (10x512 table)
//  - recurrent weights fp16 in VGPRs (1 col/thread, 512 thr/block, 1 block/CU)
//  - h state: f32 master, fp16 pairs in LDS for v_dot2_f32_f16
//  - sent compressed: hbuf[b][slot][128] f32 + idx[b][t] u16
//  - epilogue: subject->beta/gamma, then LN + po/sub heads

#define SLOTS 192

typedef _Float16 f16x2 __attribute__((ext_vector_type(2)));

__device__ __forceinline__ f16x2 as_h2(unsigned int v) {
    union { unsigned int u; f16x2 h; } x; x.u = v; return x.h;
}
__device__ __forceinline__ unsigned int as_u32(f16x2 h) {
    union { unsigned int u; f16x2 h; } x; x.h = h; return x.u;
}

#if __has_builtin(__builtin_amdgcn_fdot2)
__device__ __forceinline__ float fdot2(f16x2 a, f16x2 b, float c) {
    return __builtin_amdgcn_fdot2(a, b, c, false);
}
#else
__device__ __forceinline__ float fdot2(f16x2 a, f16x2 b, float c) {
    return c + (float)a.x * (float)b.x + (float)a.y * (float)b.y;
}
#endif

__device__ __forceinline__ float fast_rcp(float x) {
#if __has_builtin(__builtin_amdgcn_rcpf)
    return __builtin_amdgcn_rcpf(x);
#else
    return 1.f / x;
#endif
}
__device__ __forceinline__ float sigm(float x) {
    x = fminf(fmaxf(x, -30.f), 30.f);
    return fast_rcp(1.f + __expf(-x));
}
__device__ __forceinline__ float tanh_fast(float x) {
    x = fminf(fmaxf(x, -15.f), 15.f);
    float e = __expf(-2.f * x);
    return (1.f - e) * fast_rcp(1.f + e);
}

// ---------------- P0: XW1 table (10 x 512) ----------------
__global__ void k_xw1(const float* __restrict__ emb_char,
                      const float* __restrict__ emb_word,
                      const float* __restrict__ Wwc,
                      const float* __restrict__ bwc,
                      const float* __restrict__ l1_Wx,
                      const float* __restrict__ l1_b,
                      float* __restrict__ XW1) {
    __shared__ float xw[64];
    const int w = blockIdx.x;      // word id 0..9
    const int T = threadIdx.x;     // 0..511
    if (T < 64) {
        float acc = emb_char[T] + bwc[T];   // emb_char row 0
        for (int m = 0; m < 32; ++m) acc += emb_word[w * 32 + m] * Wwc[m * 64 + T];
        xw[T] = acc;
    }
    __syncthreads();
    float acc = l1_b[T];
    for (int k = 0; k < 64; ++k) acc += xw[k] * l1_Wx[k * 512 + T];
    XW1[w * 512 + T] = acc;
}

// ---------------- P1: pack 3 recurrent matrices to fp16, k-oct per column ----
// dst[ko*512 + j] packs k = 8*ko .. 8*ko+7 of column j (W row-major (128,512))
__global__ void k_pack(const float* __restrict__ l1_Wh,
                       const float* __restrict__ l2_Wx,
                       const float* __restrict__ l2_Wh,
                       uint4* __restrict__ W1p, uint4* __restrict__ WXp,
                       uint4* __restrict__ WHp) {
    const int gid = blockIdx.x * blockDim.x + threadIdx.x;  // 24576 total
    const int m  = gid >> 13;
    const int r  = gid & 8191;
    const int ko = r >> 9;
    const int j  = r & 511;
    const float* src = (m == 0) ? l1_Wh : (m == 1) ? l2_Wx : l2_Wh;
    uint4* dst       = (m == 0) ? W1p   : (m == 1) ? WXp   : WHp;
    union { uint4 q; f16x2 h[4]; } out;
    for (int e = 0; e < 4; ++e) {
        f16x2 p;
        p.x = (_Float16)src[(ko * 8 + 2 * e) * 512 + j];
        p.y = (_Float16)src[(ko * 8 + 2 * e + 1) * 512 + j];
        out.h[e] = p;
    }
    dst[ko * 512 + j] = out.q;
}

// ---------------- main recurrent kernel: 1 block per batch row ---------------
__global__ __launch_bounds__(512, 2) void k_lstm(
    const int* __restrict__ char_ids, const int* __restrict__ word_ids,
    const float* __restrict__ XW1, const uint4* __restrict__ W1p,
    const uint4* __restrict__ WXp, const uint4* __restrict__ WHp,
    const float* __restrict__ l2_b, float* __restrict__ hbuf,
    unsigned short* __restrict__ idxbuf)
{
    const int b    = blockIdx.x;
    const int T    = threadIdx.x;   // 0..511, owns z-column T
    const int lane = T & 63;
    const int wv   = T >> 6;        // 0..7

    __shared__ int   charL[512];
    __shared__ int   wordL[512];
    __shared__ float zbuf[512];
    __shared__ uint4 h1v[16];       // 128 h1 values as fp16 pairs
    __shared__ uint4 h2v[16];
    __shared__ short actT[512];
    __shared__ int   ccnt[8];

    charL[T] = char_ids[b * 512 + T];
    wordL[T] = word_ids[b * 512 + T];
    __syncthreads();

    // compact the active-step list (ordered) + write idx map
    const bool act = (charL[T] == 0);
    const unsigned long long bmask = __ballot(act);
    if (lane == 0) ccnt[wv] = (int)__popcll(bmask);
    __syncthreads();
    int base = 0;
    for (int i = 0; i < wv; ++i) base += ccnt[i];
    int tot = base;
    for (int i = wv; i < 8; ++i) tot += ccnt[i];
    if (act) actT[base + (int)__popcll(bmask & ((1ull << lane) - 1ull))] = (short)T;
    {
        int cin = base + (int)__popcll(bmask & ((2ull << lane) - 1ull));
        idxbuf[b * 512 + T] = (unsigned short)(cin < SLOTS - 1 ? cin : SLOTS - 1);
    }
    const int nact = tot;

    // init state
    if (T < 16) { h1v[T] = make_uint4(0,0,0,0); h2v[T] = make_uint4(0,0,0,0); }
    if (T < 128) hbuf[(size_t)b * SLOTS * 128 + T] = 0.f;   // slot 0 = zeros
    float c1x = 0.f, c1y = 0.f, c2x = 0.f, c2y = 0.f;       // gate threads T<64

    // persistent fp16 weight columns in VGPRs (48 x uint4 = 192 VGPRs)
    uint4 w1[16], wx[16], wh[16];
#pragma unroll
    for (int ko = 0; ko < 16; ++ko) {
        w1[ko] = W1p[ko * 512 + T];
        wx[ko] = WXp[ko * 512 + T];
        wh[ko] = WHp[ko * 512 + T];
    }
    const float l2b = l2_b[T];
    __syncthreads();

    for (int a = 0; a < nact; ++a) {
        const int t = actT[a];
        const float xw = XW1[wordL[t] * 512 + T];   // issued early, used at end

        // ---- layer 1: z1 = XW1[w] + h1 @ l1_Wh ----
        float p0 = 0.f, p1 = 0.f;
#pragma unroll
        for (int ko = 0; ko < 16; ++ko) {
            const uint4 hq = h1v[ko];
            p0 = fdot2(as_h2(hq.x), as_h2(w1[ko].x), p0);
            p1 = fdot2(as_h2(hq.y), as_h2(w1[ko].y), p1);
            p0 = fdot2(as_h2(hq.z), as_h2(w1[ko].z), p0);
            p1 = fdot2(as_h2(hq.w), as_h2(w1[ko].w), p1);
        }
        zbuf[T] = (p0 + p1) + xw;
        __syncthreads();

        if (T < 64) {   // gates layer 1, units 2T, 2T+1
            const int u0 = 2 * T;
            const float2 zi = *(const float2*)&zbuf[u0];
            const float2 zf = *(const float2*)&zbuf[128 + u0];
            const float2 zg = *(const float2*)&zbuf[256 + u0];
            const float2 zo = *(const float2*)&zbuf[384 + u0];
            c1x = sigm(zf.x) * c1x + sigm(zi.x) * tanh_fast(zg.x);
            c1y = sigm(zf.y) * c1y + sigm(zi.y) * tanh_fast(zg.y);
            f16x2 hp;
            hp.x = (_Float16)(sigm(zo.x) * tanh_fast(c1x));
            hp.y = (_Float16)(sigm(zo.y) * tanh_fast(c1y));
            ((unsigned int*)h1v)[T] = as_u32(hp);
        }
        __syncthreads();

        // ---- layer 2: z2 = l2_b + h1n @ l2_Wx + h2 @ l2_Wh ----
        float r0 = 0.f, r1 = 0.f, s0 = 0.f, s1 = 0.f;
#pragma unroll
        for (int ko = 0; ko < 16; ++ko) {
            const uint4 aq = h1v[ko];
            const uint4 bq = h2v[ko];
            r0 = fdot2(as_h2(aq.x), as_h2(wx[ko].x), r0);
            s0 = fdot2(as_h2(bq.x), as_h2(wh[ko].x), s0);
            r1 = fdot2(as_h2(aq.y), as_h2(wx[ko].y), r1);
            s1 = fdot2(as_h2(bq.y), as_h2(wh[ko].y), s1);
            r0 = fdot2(as_h2(aq.z), as_h2(wx[ko].z), r0);
            s0 = fdot2(as_h2(bq.z), as_h2(wh[ko].z), s0);
            r1 = fdot2(as_h2(aq.w), as_h2(wx[ko].w), r1);
            s1 = fdot2(as_h2(bq.w), as_h2(wh[ko].w), s1);
        }
        zbuf[T] = ((r0 + r1) + (s0 + s1)) + l2b;
        __syncthreads();

        if (T < 64) {   // gates layer 2 + hbuf write
            const int u0 = 2 * T;
            const float2 zi = *(const float2*)&zbuf[u0];
            const float2 zf = *(const float2*)&zbuf[128 + u0];
            const float2 zg = *(const float2*)&zbuf[256 + u0];
            const float2 zo = *(const float2*)&zbuf[384 + u0];
            c2x = sigm(zf.x) * c2x + sigm(zi.x) * tanh_fast(zg.x);
            c2y = sigm(zf.y) * c2y + sigm(zi.y) * tanh_fast(zg.y);
            const float h20 = sigm(zo.x) * tanh_fast(c2x);
            const float h21 = sigm(zo.y) * tanh_fast(c2y);
            f16x2 hp; hp.x = (_Float16)h20; hp.y = (_Float16)h21;
            ((unsigned int*)h2v)[T] = as_u32(hp);
            const int slot = (a + 1 < SLOTS - 1) ? a + 1 : SLOTS - 1;
            float2 hw; hw.x = h20; hw.y = h21;
            *(float2*)&hbuf[((size_t)b * SLOTS + slot) * 128 + u0] = hw;
        }
        __syncthreads();
    }
}

// ---------------- C1: subject gather -> beta/gamma per row -------------------
__global__ void k_subject(const int* __restrict__ subject_ids,
                          const unsigned short* __restrict__ idxbuf,
                          const float* __restrict__ hbuf,
                          const float* __restrict__ beta_W, const float* __restrict__ beta_b,
                          const float* __restrict__ gamma_W, const float* __restrict__ gamma_b,
                          float* __restrict__ betaO, float* __restrict__ gammaO)
{
    const int b = blockIdx.x;
    const int u = threadIdx.x;   // 0..127
    __shared__ float subj[256];
    const int s0 = subject_ids[b * 2 + 0];
    const int s1 = subject_ids[b * 2 + 1];
    const int i0 = idxbuf[b * 512 + s0];
    const int i1 = idxbuf[b * 512 + s1];
    subj[u]       = hbuf[((size_t)b * SLOTS + i0) * 128 + u];
    subj[128 + u] = hbuf[((size_t)b * SLOTS + i1) * 128 + u];
    __syncthreads();
    float ab = beta_b[u], ag = gamma_b[u];
    for (int c = 0; c < 256; ++c) {
        const float s = subj[c];
        ab += s * beta_W[c * 128 + u];
        ag += s * gamma_W[c * 128 + u];
    }
    betaO[b * 128 + u]  = ab;
    gammaO[b * 128 + u] = ag;
}

// ---------------- C2: LayerNorm + po / sub heads ----------------------------
__global__ __launch_bounds__(256) void k_out(
    const unsigned short* __restrict__ idxbuf, const float* __restrict__ hbuf,
    const float* __restrict__ betaO, const float* __restrict__ gammaO,
    const float* __restrict__ sub_W, const float* __restrict__ sub_b,
    const float* __restrict__ po_W, const float* __restrict__ po_b,
    float* __restrict__ out)
{
    const int blk = blockIdx.x;
    const int b  = blk >> 6;
    const int t0 = (blk & 63) * 8;
    const int T  = threadIdx.x;
    __shared__ float hv[8][132];
    __shared__ float ctx[8][132];
    __shared__ float gm[128], bt[128];
    __shared__ float um[8], rs[8];
    __shared__ float pw[2560];
    if (T < 128) { gm[T] = gammaO[b * 128 + T]; bt[T] = betaO[b * 128 + T]; }
    for (int i = T; i < 2560; i += 256) pw[i] = po_W[i];
    const int tt = T >> 5, l = T & 31;
    const int id = idxbuf[b * 512 + t0 + tt];
    const float4 hq = *(const float4*)&hbuf[((size_t)b * SLOTS + id) * 128 + l * 4];
    *(float4*)&hv[tt][l * 4] = hq;
    float s  = (hq.x + hq.y) + (hq.z + hq.w);
    float s2 = hq.x * hq.x + hq.y * hq.y + hq.z * hq.z + hq.w * hq.w;
    for (int d = 16; d > 0; d >>= 1) {
        s  += __shfl_down(s, d, 32);
        s2 += __shfl_down(s2, d, 32);
    }
    if (l == 0) {
        const float u = s * (1.f / 128.f);
        const float v = fmaxf(s2 * (1.f / 128.f) - u * u, 0.f);
        um[tt] = u;
        rs[tt] = 1.f / sqrtf(v + 1e-12f);
    }
    __syncthreads();
    for (int i = T; i < 1024; i += 256) {
        const int t2 = i >> 7, c = i & 127;
        ctx[t2][c] = gm[c] * (hv[t2][c] - um[t2]) * rs[t2] + bt[c];
    }
    __syncthreads();
    if (T < 160) {
        const int t2 = T / 20;
        const int o  = T - t2 * 20;
        float acc = po_b[o];
        for (int c = 0; c < 128; ++c) acc += ctx[t2][c] * pw[c * 20 + o];
        out[262144 + ((size_t)(b * 512 + t0 + t2) * 20 + o)] = acc;
    } else if (T < 176) {
        const int r  = T - 160;
        const int t2 = r >> 1, o = r & 1;
        float acc = sub_b[o];
        for (int c = 0; c < 128; ++c) acc += hv[t2][c] * sub_W[c * 2 + o];
        out[(size_t)(b * 512 + t0 + t2) * 2 + o] = acc;
    }
}

extern "C" void kernel_launch(void* const* d_in, const int* in_sizes, int n_in,
                              void* d_out, int out_size, void* d_ws, size_t ws_size,
                              hipStream_t stream) {
    (void)in_sizes; (void)n_in; (void)out_size; (void)ws_size;
    const int*   char_ids    = (const int*)d_in[0];
    const int*   word_ids    = (const int*)d_in[1];
    const int*   subject_ids = (const int*)d_in[2];
    const float* emb_char    = (const float*)d_in[3];
    const float* emb_word    = (const float*)d_in[4];
    const float* Wwc         = (const float*)d_in[5];
    const float* bwc         = (const float*)d_in[6];
    const float* l1_Wx       = (const float*)d_in[7];
    const float* l1_Wh       = (const float*)d_in[8];
    const float* l1_b        = (const float*)d_in[9];
    const float* l2_Wx       = (const float*)d_in[10];
    const float* l2_Wh       = (const float*)d_in[11];
    const float* l2_b        = (const float*)d_in[12];
    const float* beta_W      = (const float*)d_in[13];
    const float* beta_b      = (const float*)d_in[14];
    const float* gamma_W     = (const float*)d_in[15];
    const float* gamma_b     = (const float*)d_in[16];
    const float* sub_W       = (const float*)d_in[17];
    const float* sub_b       = (const float*)d_in[18];
    const float* po_W        = (const float*)d_in[19];
    const float* po_b        = (const float*)d_in[20];
    float* out = (float*)d_out;

    char* ws = (char*)d_ws;
    float*          XW1    = (float*)(ws + 0);          // 20480 B
    uint4*          W1p    = (uint4*)(ws + 32768);      // 131072 B
    uint4*          WXp    = (uint4*)(ws + 163840);     // 131072 B
    uint4*          WHp    = (uint4*)(ws + 294912);     // 131072 B
    float*          betaO  = (float*)(ws + 425984);     // 131072 B
    float*          gammaO = (float*)(ws + 557056);     // 131072 B
    unsigned short* idxbuf = (unsigned short*)(ws + 688128);  // 262144 B
    float*          hbuf   = (float*)(ws + 950272);     // 256*192*128*4 = 25165824 B

    k_xw1<<<dim3(10), dim3(512), 0, stream>>>(emb_char, emb_word, Wwc, bwc, l1_Wx, l1_b, XW1);
    k_pack<<<dim3(96), dim3(256), 0, stream>>>(l1_Wh, l2_Wx, l2_Wh, W1p, WXp, WHp);
    k_lstm<<<dim3(256), dim3(512), 0, stream>>>(char_ids, word_ids, XW1, W1p, WXp, WHp,
                                                l2_b, hbuf, idxbuf);
    k_subject<<<dim3(256), dim3(128), 0, stream>>>(subject_ids, idxbuf, hbuf,
                                                   beta_W, beta_b, gamma_W, gamma_b,
                                                   betaO, gammaO);
    k_out<<<dim3(16384), dim3(256), 0, stream>>>(idxbuf, hbuf, betaO, gammaO,
                                                 sub_W, sub_b, po_W, po_b, out);
}

// Round 2
// 271.399 us; speedup vs baseline: 1.1428x; 1.1428x over previous
//
#include <hip/hip_runtime.h>
#include <cstdint>
#include <cstddef>

// PointerNetwork: B=256, S=512, H=128, CHAR/CLASS=10, OUT=64, WE=32
// R1 design:
//  - active-step skipping (char_ids==0, ~51-71/512 steps per row)
//  - k_lstm: k-slice split (q=T&7 owns 1/8 of K; g=T>>3 owns 8 cols),
//    DPP butterfly (xor1/xor2/half-mirror) reduces partials in-register.
//    fp16 weights pinned in VGPRs via asm barrier (192 regs/thread).
//  - epilogue: per-slot LN+po/sub with LN folded algebraically, then scatter.

#define SLOTS 192

typedef _Float16 f16x2 __attribute__((ext_vector_type(2)));

__device__ __forceinline__ f16x2 as_h2(unsigned int v) {
    union { unsigned int u; f16x2 h; } x; x.u = v; return x.h;
}

#if __has_builtin(__builtin_amdgcn_fdot2)
__device__ __forceinline__ float fdot2(f16x2 a, f16x2 b, float c) {
    return __builtin_amdgcn_fdot2(a, b, c, false);
}
#else
__device__ __forceinline__ float fdot2(f16x2 a, f16x2 b, float c) {
    return c + (float)a.x * (float)b.x + (float)a.y * (float)b.y;
}
#endif

__device__ __forceinline__ float fast_rcp(float x) {
#if __has_builtin(__builtin_amdgcn_rcpf)
    return __builtin_amdgcn_rcpf(x);
#else
    return 1.f / x;
#endif
}
__device__ __forceinline__ float sigm(float x) {
    x = fminf(fmaxf(x, -30.f), 30.f);
    return fast_rcp(1.f + __expf(-x));
}
__device__ __forceinline__ float tanh_fast(float x) {
    x = fminf(fmaxf(x, -15.f), 15.f);
    float e = __expf(-2.f * x);
    return (1.f - e) * fast_rcp(1.f + e);
}

// xor-butterfly add over lane groups of 8 (q = lane&7) via DPP, VALU-only.
__device__ __forceinline__ float dpp_bfly8(float v) {
    union { float f; int i; } a, b;
    a.f = v;
    b.i = __builtin_amdgcn_update_dpp(0, a.i, 0xB1, 0xf, 0xf, true);   // quad_perm xor1
    a.f += b.f;
    b.i = __builtin_amdgcn_update_dpp(0, a.i, 0x4E, 0xf, 0xf, true);   // quad_perm xor2
    a.f += b.f;
    b.i = __builtin_amdgcn_update_dpp(0, a.i, 0x141, 0xf, 0xf, true);  // row_half_mirror (xor7≡xor4 here)
    a.f += b.f;
    return a.f;
}

// ---------------- P0: XW1 table (10 x 512) ----------------
__global__ void k_xw1(const float* __restrict__ emb_char,
                      const float* __restrict__ emb_word,
                      const float* __restrict__ Wwc,
                      const float* __restrict__ bwc,
                      const float* __restrict__ l1_Wx,
                      const float* __restrict__ l1_b,
                      float* __restrict__ XW1) {
    __shared__ float xw[64];
    const int w = blockIdx.x;      // word id 0..9
    const int T = threadIdx.x;     // 0..511
    if (T < 64) {
        float acc = emb_char[T] + bwc[T];   // emb_char row 0
        for (int m = 0; m < 32; ++m) acc += emb_word[w * 32 + m] * Wwc[m * 64 + T];
        xw[T] = acc;
    }
    __syncthreads();
    float acc = l1_b[T];
    for (int k = 0; k < 64; ++k) acc += xw[k] * l1_Wx[k * 512 + T];
    XW1[w * 512 + T] = acc;
}

// ---------------- P1: pack weights fp16, per-(thread,slice) contiguous -------
// W1H[t*16 + j*2 + u]: thread t=(q=t&7,g=t>>3), col=8g+j, k-pairs P=4u+e, k=16q+2P
// W2H[t*32 + j*4 + u]: k=32q+2P (P=4u+e); k<128 -> l2_Wx row k, else l2_Wh row k-128
__global__ void k_pack2(const float* __restrict__ l1_Wh,
                        const float* __restrict__ l2_Wx,
                        const float* __restrict__ l2_Wh,
                        uint4* __restrict__ W1H, uint4* __restrict__ W2H) {
    const int gid = blockIdx.x * blockDim.x + threadIdx.x;  // 24576 total
    union { uint4 qv; f16x2 h[4]; } out;
    if (gid < 8192) {
        const int t = gid >> 4, i = gid & 15;
        const int q = t & 7, g = t >> 3;
        const int j = i >> 1, u = i & 1;
        const int col = 8 * g + j;
        for (int e = 0; e < 4; ++e) {
            const int k = 16 * q + 2 * (4 * u + e);
            f16x2 p;
            p.x = (_Float16)l1_Wh[k * 512 + col];
            p.y = (_Float16)l1_Wh[(k + 1) * 512 + col];
            out.h[e] = p;
        }
        W1H[gid] = out.qv;
    } else {
        const int gid2 = gid - 8192;
        const int t = gid2 >> 5, i = gid2 & 31;
        const int q = t & 7, g = t >> 3;
        const int j = i >> 2, u = i & 3;
        const int col = 8 * g + j;
        for (int e = 0; e < 4; ++e) {
            const int kk = 32 * q + 2 * (4 * u + e);   // 0..254, even
            float w0, w1v;
            if (kk < 128) { w0 = l2_Wx[kk * 512 + col];        w1v = l2_Wx[(kk + 1) * 512 + col]; }
            else          { w0 = l2_Wh[(kk - 128) * 512 + col]; w1v = l2_Wh[(kk - 127) * 512 + col]; }
            f16x2 p; p.x = (_Float16)w0; p.y = (_Float16)w1v;
            out.h[e] = p;
        }
        W2H[gid2] = out.qv;
    }
}

// ---------------- main recurrent kernel: 1 block per batch row ---------------
__global__ __launch_bounds__(512, 2) void k_lstm(
    const int* __restrict__ char_ids, const int* __restrict__ word_ids,
    const float* __restrict__ XW1, const uint4* __restrict__ W1H,
    const uint4* __restrict__ W2H, const float* __restrict__ l2_b,
    float* __restrict__ hbuf, unsigned short* __restrict__ idxbuf)
{
    const int b    = blockIdx.x;
    const int T    = threadIdx.x;   // 0..511
    const int lane = T & 63;
    const int wv   = T >> 6;        // 0..7
    const int q    = T & 7;         // k-slice
    const int g    = T >> 3;        // column group: cols 8g..8g+7

    __shared__ int   charL[512];
    __shared__ int   wordL[512];
    __shared__ float zsum1[512];
    __shared__ float zsum2[512];
    __shared__ _Float16 h1f[128];
    __shared__ _Float16 h2f[128];
    __shared__ short actT[512];
    __shared__ int   ccnt[8];

    charL[T] = char_ids[b * 512 + T];
    wordL[T] = word_ids[b * 512 + T];
    __syncthreads();

    // compact the active-step list (ordered) + write idx map
    const bool act = (charL[T] == 0);
    const unsigned long long bmask = __ballot(act);
    if (lane == 0) ccnt[wv] = (int)__popcll(bmask);
    __syncthreads();
    int base = 0;
    for (int i = 0; i < wv; ++i) base += ccnt[i];
    int tot = base;
    for (int i = wv; i < 8; ++i) tot += ccnt[i];
    if (act) actT[base + (int)__popcll(bmask & ((1ull << lane) - 1ull))] = (short)T;
    {
        int cin = base + (int)__popcll(bmask & ((2ull << lane) - 1ull));
        idxbuf[b * 512 + T] = (unsigned short)(cin < SLOTS - 1 ? cin : SLOTS - 1);
    }
    const int nact = tot;

    // init state
    if (T < 128) {
        h1f[T] = (_Float16)0.f;
        h2f[T] = (_Float16)0.f;
        hbuf[(size_t)b * SLOTS * 128 + T] = 0.f;   // slot 0 = zeros
    }
    float c1 = 0.f, c2 = 0.f;        // gate threads T<128, unit u=T
    float l2b0 = 0.f, l2b1 = 0.f, l2b2 = 0.f, l2b3 = 0.f;
    if (T < 128) {
        l2b0 = l2_b[T]; l2b1 = l2_b[128 + T]; l2b2 = l2_b[256 + T]; l2b3 = l2_b[384 + T];
    }

    // persistent fp16 weight slices in VGPRs (48 x uint4 = 192 VGPRs)
    uint4 w1[16], w2[32];
    {
        const uint4* W1t = W1H + (size_t)T * 16;
        const uint4* W2t = W2H + (size_t)T * 32;
#pragma unroll
        for (int i = 0; i < 16; ++i) w1[i] = W1t[i];
#pragma unroll
        for (int i = 0; i < 32; ++i) w2[i] = W2t[i];
    }
#pragma unroll
    for (int i = 0; i < 16; ++i)
        asm volatile("" : "+v"(w1[i].x), "+v"(w1[i].y), "+v"(w1[i].z), "+v"(w1[i].w));
#pragma unroll
    for (int i = 0; i < 32; ++i)
        asm volatile("" : "+v"(w2[i].x), "+v"(w2[i].y), "+v"(w2[i].z), "+v"(w2[i].w));

    const uint4* h1q = (const uint4*)h1f;
    const uint4* h2q = (const uint4*)h2f;
    __syncthreads();

    for (int a = 0; a < nact; ++a) {
        const int t = actT[a];
        // gate threads prefetch XW1 row entries (hidden behind phase A)
        float xwi = 0.f, xwf = 0.f, xwg = 0.f, xwo = 0.f;
        if (T < 128) {
            const float* xr = XW1 + wordL[t] * 512 + T;
            xwi = xr[0]; xwf = xr[128]; xwg = xr[256]; xwo = xr[384];
        }

        // ---- phase A: layer-1 partial dots on k-slice q, cols 8g..8g+7 ----
        {
            const uint4 ha = h1q[2 * q];
            const uint4 hb = h1q[2 * q + 1];
            float acc[8];
#pragma unroll
            for (int j = 0; j < 8; ++j) {
                const uint4 wA = w1[2 * j], wB = w1[2 * j + 1];
                float s = fdot2(as_h2(ha.x), as_h2(wA.x), 0.f);
                s = fdot2(as_h2(ha.y), as_h2(wA.y), s);
                s = fdot2(as_h2(ha.z), as_h2(wA.z), s);
                s = fdot2(as_h2(ha.w), as_h2(wA.w), s);
                s = fdot2(as_h2(hb.x), as_h2(wB.x), s);
                s = fdot2(as_h2(hb.y), as_h2(wB.y), s);
                s = fdot2(as_h2(hb.z), as_h2(wB.z), s);
                s = fdot2(as_h2(hb.w), as_h2(wB.w), s);
                acc[j] = dpp_bfly8(s);
            }
            if (q == 0) {
                *(float4*)&zsum1[8 * g]     = make_float4(acc[0], acc[1], acc[2], acc[3]);
                *(float4*)&zsum1[8 * g + 4] = make_float4(acc[4], acc[5], acc[6], acc[7]);
            }
        }
        __syncthreads();

        // ---- phase B: layer-1 gates (unit u = T) ----
        if (T < 128) {
            const float zi = zsum1[T]       + xwi;
            const float zf = zsum1[128 + T] + xwf;
            const float zg = zsum1[256 + T] + xwg;
            const float zo = zsum1[384 + T] + xwo;
            c1 = sigm(zf) * c1 + sigm(zi) * tanh_fast(zg);
            h1f[T] = (_Float16)(sigm(zo) * tanh_fast(c1));
        }
        __syncthreads();

        // ---- phase C: layer-2 partial dots (K=256 concat [h1n; h2]) ----
        {
            const uint4* hsrc = (q < 4) ? (h1q + 4 * q) : (h2q + 4 * (q - 4));
            const uint4 h0 = hsrc[0], h1_ = hsrc[1], h2_ = hsrc[2], h3_ = hsrc[3];
            float acc[8];
#pragma unroll
            for (int j = 0; j < 8; ++j) {
                const uint4 wA = w2[4 * j], wB = w2[4 * j + 1];
                const uint4 wC = w2[4 * j + 2], wD = w2[4 * j + 3];
                float s = fdot2(as_h2(h0.x), as_h2(wA.x), 0.f);
                s = fdot2(as_h2(h0.y), as_h2(wA.y), s);
                s = fdot2(as_h2(h0.z), as_h2(wA.z), s);
                s = fdot2(as_h2(h0.w), as_h2(wA.w), s);
                s = fdot2(as_h2(h1_.x), as_h2(wB.x), s);
                s = fdot2(as_h2(h1_.y), as_h2(wB.y), s);
                s = fdot2(as_h2(h1_.z), as_h2(wB.z), s);
                s = fdot2(as_h2(h1_.w), as_h2(wB.w), s);
                s = fdot2(as_h2(h2_.x), as_h2(wC.x), s);
                s = fdot2(as_h2(h2_.y), as_h2(wC.y), s);
                s = fdot2(as_h2(h2_.z), as_h2(wC.z), s);
                s = fdot2(as_h2(h2_.w), as_h2(wC.w), s);
                s = fdot2(as_h2(h3_.x), as_h2(wD.x), s);
                s = fdot2(as_h2(h3_.y), as_h2(wD.y), s);
                s = fdot2(as_h2(h3_.z), as_h2(wD.z), s);
                s = fdot2(as_h2(h3_.w), as_h2(wD.w), s);
                acc[j] = dpp_bfly8(s);
            }
            if (q == 0) {
                *(float4*)&zsum2[8 * g]     = make_float4(acc[0], acc[1], acc[2], acc[3]);
                *(float4*)&zsum2[8 * g + 4] = make_float4(acc[4], acc[5], acc[6], acc[7]);
            }
        }
        __syncthreads();

        // ---- phase D: layer-2 gates + hbuf write ----
        if (T < 128) {
            const float zi = zsum2[T]       + l2b0;
            const float zf = zsum2[128 + T] + l2b1;
            const float zg = zsum2[256 + T] + l2b2;
            const float zo = zsum2[384 + T] + l2b3;
            c2 = sigm(zf) * c2 + sigm(zi) * tanh_fast(zg);
            const float h2v = sigm(zo) * tanh_fast(c2);
            h2f[T] = (_Float16)h2v;
            const int slot = (a + 1 < SLOTS - 1) ? a + 1 : SLOTS - 1;
            hbuf[((size_t)b * SLOTS + slot) * 128 + T] = h2v;
        }
        __syncthreads();
    }
}

// ---------------- C1: subject gather -> beta/gamma per row -------------------
__global__ void k_subject(const int* __restrict__ subject_ids,
                          const unsigned short* __restrict__ idxbuf,
                          const float* __restrict__ hbuf,
                          const float* __restrict__ beta_W, const float* __restrict__ beta_b,
                          const float* __restrict__ gamma_W, const float* __restrict__ gamma_b,
                          float* __restrict__ betaO, float* __restrict__ gammaO)
{
    const int b = blockIdx.x;
    const int u = threadIdx.x;   // 0..127
    __shared__ float subj[256];
    const int s0 = subject_ids[b * 2 + 0];
    const int s1 = subject_ids[b * 2 + 1];
    const int i0 = idxbuf[b * 512 + s0];
    const int i1 = idxbuf[b * 512 + s1];
    subj[u]       = hbuf[((size_t)b * SLOTS + i0) * 128 + u];
    subj[128 + u] = hbuf[((size_t)b * SLOTS + i1) * 128 + u];
    __syncthreads();
    float ab = beta_b[u], ag = gamma_b[u];
    for (int c = 0; c < 256; ++c) {
        const float s = subj[c];
        ab += s * beta_W[c * 128 + u];
        ag += s * gamma_W[c * 128 + u];
    }
    betaO[b * 128 + u]  = ab;
    gammaO[b * 128 + u] = ag;
}

// ---------------- C2: per-slot LN + po/sub heads, then scatter ---------------
// po(s,o) = rs*sum_c(gm[c]*pw[c][o]*h[s][c]) - u*rs*K2[o] + K1[o]
//   K1[o] = po_b[o] + sum_c bt[c]*pw[c][o];  K2[o] = sum_c gm[c]*pw[c][o]
__global__ __launch_bounds__(256) void k_out2(
    const unsigned short* __restrict__ idxbuf, const float* __restrict__ hbuf,
    const float* __restrict__ betaO, const float* __restrict__ gammaO,
    const float* __restrict__ sub_W, const float* __restrict__ sub_b,
    const float* __restrict__ po_W, const float* __restrict__ po_b,
    float* __restrict__ out)
{
    const int b = blockIdx.x;
    const int T = threadIdx.x;   // 0..255
    __shared__ float A[20][132];          // A[o][c] = gm[c]*po_W[c*20+o]
    __shared__ float K1[20], K2[20];
    __shared__ float gm[128], bt[128];
    __shared__ float urs[192][2];
    __shared__ float povals[192 * 20];
    __shared__ float subv[192 * 2];
    __shared__ unsigned short idxr[512];
    __shared__ float swl[256];

    if (T < 128) { gm[T] = gammaO[b * 128 + T]; bt[T] = betaO[b * 128 + T]; }
    idxr[T] = idxbuf[b * 512 + T];
    idxr[256 + T] = idxbuf[b * 512 + 256 + T];
    swl[T] = sub_W[T];
    __syncthreads();

    // A fill + K1/K2 + per-slot stats & sub head
    for (int i = T; i < 2560; i += 256) {
        const int o = i >> 7, c = i & 127;
        A[o][c] = gm[c] * po_W[c * 20 + o];
    }
    if (T < 20) {
        float k1 = po_b[T], k2 = 0.f;
        for (int c = 0; c < 128; ++c) {
            const float pw = po_W[c * 20 + T];
            k1 += bt[c] * pw;
            k2 += gm[c] * pw;
        }
        K1[T] = k1; K2[T] = k2;
    }
    const int nslot = (int)idxr[511] + 1;
    const float sb0 = sub_b[0], sb1 = sub_b[1];
    for (int s = T; s < nslot; s += 256) {
        const float4* hp4 = (const float4*)(hbuf + ((size_t)b * SLOTS + s) * 128);
        float sum = 0.f, s2 = 0.f, sub0 = sb0, sub1 = sb1;
        for (int c4 = 0; c4 < 32; ++c4) {
            const float4 h = hp4[c4];
            sum += (h.x + h.y) + (h.z + h.w);
            s2  += h.x * h.x + h.y * h.y + h.z * h.z + h.w * h.w;
            const int c = 4 * c4;
            sub0 += h.x * swl[2 * c] + h.y * swl[2 * c + 2] + h.z * swl[2 * c + 4] + h.w * swl[2 * c + 6];
            sub1 += h.x * swl[2 * c + 1] + h.y * swl[2 * c + 3] + h.z * swl[2 * c + 5] + h.w * swl[2 * c + 7];
        }
        const float u = sum * (1.f / 128.f);
        const float v = fmaxf(s2 * (1.f / 128.f) - u * u, 0.f);
        urs[s][0] = u;
        urs[s][1] = 1.f / sqrtf(v + 1e-12f);
        subv[2 * s] = sub0; subv[2 * s + 1] = sub1;
    }
    __syncthreads();

    // po head per (slot, o)
    for (int i = T; i < nslot * 20; i += 256) {
        const int s = i / 20, o = i - 20 * s;
        const float u = urs[s][0], rs = urs[s][1];
        const float4* hp4 = (const float4*)(hbuf + ((size_t)b * SLOTS + s) * 128);
        const float* Ao = &A[o][0];
        float acc = 0.f;
        for (int c4 = 0; c4 < 32; ++c4) {
            const float4 h = hp4[c4];
            const float4 aa = *(const float4*)&Ao[4 * c4];
            acc += h.x * aa.x + h.y * aa.y + h.z * aa.z + h.w * aa.w;
        }
        povals[i] = rs * acc - u * rs * K2[o] + K1[o];
    }
    __syncthreads();

    // scatter
    for (int i = T; i < 2560; i += 256) {
        const int t = i / 5, j = i - 5 * t;
        const int sl = idxr[t];
        const float4 v = *(const float4*)&povals[sl * 20 + 4 * j];
        *(float4*)&out[262144 + ((size_t)(b * 512 + t)) * 20 + 4 * j] = v;
    }
    for (int i = T; i < 512; i += 256) {
        const int sl = idxr[i];
        float2 v; v.x = subv[2 * sl]; v.y = subv[2 * sl + 1];
        *(float2*)&out[((size_t)(b * 512 + i)) * 2] = v;
    }
}

extern "C" void kernel_launch(void* const* d_in, const int* in_sizes, int n_in,
                              void* d_out, int out_size, void* d_ws, size_t ws_size,
                              hipStream_t stream) {
    (void)in_sizes; (void)n_in; (void)out_size; (void)ws_size;
    const int*   char_ids    = (const int*)d_in[0];
    const int*   word_ids    = (const int*)d_in[1];
    const int*   subject_ids = (const int*)d_in[2];
    const float* emb_char    = (const float*)d_in[3];
    const float* emb_word    = (const float*)d_in[4];
    const float* Wwc         = (const float*)d_in[5];
    const float* bwc         = (const float*)d_in[6];
    const float* l1_Wx       = (const float*)d_in[7];
    const float* l1_Wh       = (const float*)d_in[8];
    const float* l1_b        = (const float*)d_in[9];
    const float* l2_Wx       = (const float*)d_in[10];
    const float* l2_Wh       = (const float*)d_in[11];
    const float* l2_b        = (const float*)d_in[12];
    const float* beta_W      = (const float*)d_in[13];
    const float* beta_b      = (const float*)d_in[14];
    const float* gamma_W     = (const float*)d_in[15];
    const float* gamma_b     = (const float*)d_in[16];
    const float* sub_W       = (const float*)d_in[17];
    const float* sub_b       = (const float*)d_in[18];
    const float* po_W        = (const float*)d_in[19];
    const float* po_b        = (const float*)d_in[20];
    float* out = (float*)d_out;

    char* ws = (char*)d_ws;
    float*          XW1    = (float*)(ws + 0);          // 20480 B (pad to 32768)
    uint4*          W1H    = (uint4*)(ws + 32768);      // 131072 B
    uint4*          W2H    = (uint4*)(ws + 163840);     // 262144 B
    float*          betaO  = (float*)(ws + 425984);     // 131072 B
    float*          gammaO = (float*)(ws + 557056);     // 131072 B
    unsigned short* idxbuf = (unsigned short*)(ws + 688128);  // 262144 B
    float*          hbuf   = (float*)(ws + 950272);     // 256*192*128*4 = 25165824 B

    k_xw1<<<dim3(10), dim3(512), 0, stream>>>(emb_char, emb_word, Wwc, bwc, l1_Wx, l1_b, XW1);
    k_pack2<<<dim3(96), dim3(256), 0, stream>>>(l1_Wh, l2_Wx, l2_Wh, W1H, W2H);
    k_lstm<<<dim3(256), dim3(512), 0, stream>>>(char_ids, word_ids, XW1, W1H, W2H,
                                                l2_b, hbuf, idxbuf);
    k_subject<<<dim3(256), dim3(128), 0, stream>>>(subject_ids, idxbuf, hbuf,
                                                   beta_W, beta_b, gamma_W, gamma_b,
                                                   betaO, gammaO);
    k_out2<<<dim3(256), dim3(256), 0, stream>>>(idxbuf, hbuf, betaO, gammaO,
                                                sub_W, sub_b, po_W, po_b, out);
}